// Round 3
// baseline (3492.945 us; speedup 1.0000x reference)
//
#include <hip/hip_runtime.h>
#include <stdint.h>

#define B_    256
#define T_    1024
#define H_    512
#define NIN_  64
#define NOUT_ 64

// ---- rnn_scan config: 64 blocks x 4 waves; wave owns 128 cols (jt 0..7) ----
#define BBLK   4
#define SC_NW  4          // waves per block
#define KB_N   16         // K = 512 in 16 blocks of 32
#define RU     100        // reg-resident (kb,jt) units: kb 0..11 all jt + kb12 jt0..3
#define LU     28         // LDS-resident units: kb12 jt4..7 + kb 13..15 all jt (28*4KB=112KB)
#define HROW   528        // hbuf row stride (shorts): 1056B -> 8-bank shift/row

typedef __attribute__((ext_vector_type(8))) short bf16x8;
typedef __attribute__((ext_vector_type(4))) float f32x4;

__device__ __forceinline__ short f2bf(float f) {
  uint32_t u = __float_as_uint(f);
  uint32_t r = (u + 0x7FFFu + ((u >> 16) & 1u)) >> 16;
  return (short)(r & 0xFFFFu);
}

__device__ __forceinline__ bf16x8 pack8(float4 lo, float4 hi) {
  bf16x8 s;
  s[0] = f2bf(lo.x); s[1] = f2bf(lo.y); s[2] = f2bf(lo.z); s[3] = f2bf(lo.w);
  s[4] = f2bf(hi.x); s[5] = f2bf(hi.y); s[6] = f2bf(hi.z); s[7] = f2bf(hi.w);
  return s;
}

__device__ __forceinline__ float fast_tanh(float x) {
  float e = __expf(2.0f * x);
  return 1.0f - __fdividef(2.0f, e + 1.0f);
}

// ---------------------------------------------------------------------------
// xproj: inp[b,t,h] = X[b,t,:] @ Win[h,:]  (f32 out, written into hid region)
// 512-thr blocks; wave w owns cols 64w..64w+63; block grid-strides 16-row tiles.
// ---------------------------------------------------------------------------
#define XP_BLOCKS 512
__global__ __launch_bounds__(512, 2) void xproj(
    const float* __restrict__ X, const float* __restrict__ Win,
    float* __restrict__ inp)
{
  const int tid  = threadIdx.x;
  const int lane = tid & 63;
  const int w    = tid >> 6;
  const int g    = lane >> 4;
  const int m    = lane & 15;

  // B-fragments: 2 kb x 4 jt = 8 units = 32 VGPR
  bf16x8 Bf[2][4];
#pragma unroll
  for (int kb = 0; kb < 2; ++kb)
#pragma unroll
    for (int jt = 0; jt < 4; ++jt) {
      const int j = 64 * w + 16 * jt + m;
      const float4* p = reinterpret_cast<const float4*>(Win + (size_t)j * NIN_ + 32 * kb + 8 * g);
      Bf[kb][jt] = pack8(p[0], p[1]);
    }

  const int NTILES = (B_ * T_) / 16;
  const f32x4 zero = {0.f, 0.f, 0.f, 0.f};

  for (int tile = blockIdx.x; tile < NTILES; tile += XP_BLOCKS) {
    const size_t row0 = (size_t)tile * 16;
    f32x4 acc[4];
    {
      const float4* p = reinterpret_cast<const float4*>(X + (row0 + m) * NIN_ + 8 * g);
      const bf16x8 a = pack8(p[0], p[1]);
#pragma unroll
      for (int jt = 0; jt < 4; ++jt)
        acc[jt] = __builtin_amdgcn_mfma_f32_16x16x32_bf16(a, Bf[0][jt], zero, 0, 0, 0);
    }
    {
      const float4* p = reinterpret_cast<const float4*>(X + (row0 + m) * NIN_ + 32 + 8 * g);
      const bf16x8 a = pack8(p[0], p[1]);
#pragma unroll
      for (int jt = 0; jt < 4; ++jt)
        acc[jt] = __builtin_amdgcn_mfma_f32_16x16x32_bf16(a, Bf[1][jt], acc[jt], 0, 0, 0);
    }
#pragma unroll
    for (int jt = 0; jt < 4; ++jt)
#pragma unroll
      for (int r = 0; r < 4; ++r)
        inp[(row0 + 4 * g + r) * H_ + 64 * w + 16 * jt + m] = acc[jt][r];
  }
}

// ---------------------------------------------------------------------------
// rnn_scan: persistent; 64 blocks x 256 thr (4 waves, 1 wave/SIMD, cap 512 VGPR).
// Wave w owns cols [128w,128w+128). W split: 100 units in VGPR, 28 in LDS.
// A = tanh(h) in double-buffered LDS; 1 barrier/step, lgkm-only drain.
// inp read from hid region (pre-filled by xproj), overwritten with h in place.
// ---------------------------------------------------------------------------
__global__ __launch_bounds__(SC_NW * 64, 1) void rnn_scan(
    const float* __restrict__ h0, const float* __restrict__ W,
    float* __restrict__ hid)
{
  __shared__ __align__(16) short wlds[LU][64][32];      // 28 * 4KB = 112 KB
  __shared__ __align__(16) short hbuf[2][BBLK][HROW];   // 8.25 KB

  const int tid  = threadIdx.x;
  const int lane = tid & 63;
  const int w    = tid >> 6;    // wave 0..3
  const int g    = lane >> 4;
  const int m    = lane & 15;
  const int b0   = blockIdx.x * BBLK;

  // --- register-resident W units: kb 0..11 all jt (96) + kb12 jt0..3 (4)
  bf16x8 Wf[RU];
#pragma unroll
  for (int kb = 0; kb < 12; ++kb)
#pragma unroll
    for (int jt = 0; jt < 8; ++jt) {
      const int j = 128 * w + 16 * jt + m;
      const float4* p = reinterpret_cast<const float4*>(W + (size_t)j * H_ + 32 * kb + 8 * g);
      Wf[kb * 8 + jt] = pack8(p[0], p[1]);
    }
#pragma unroll
  for (int jt = 0; jt < 4; ++jt) {
    const int j = 128 * w + 16 * jt + m;
    const float4* p = reinterpret_cast<const float4*>(W + (size_t)j * H_ + 32 * 12 + 8 * g);
    Wf[96 + jt] = pack8(p[0], p[1]);
  }

  // --- stage LDS-resident W units: u<4 -> (kb=12, jt=4+u); else (kb=13+(v>>3), jt=v&7)
  // 28 units * 64 colslots * 4 chunks = 7168 chunks of 8 shorts; 28 per thread
#pragma unroll
  for (int i = 0; i < LU; ++i) {
    const int c  = tid + 256 * i;
    const int u  = c >> 8;
    const int s  = c & 255;
    const int wm = s >> 2;          // w*16+m
    const int gq = s & 3;
    int kb, jt;
    if (u < 4) { kb = 12; jt = 4 + u; } else { kb = 13 + ((u - 4) >> 3); jt = (u - 4) & 7; }
    const int j = 128 * (wm >> 4) + 16 * jt + (wm & 15);
    const float4* p = reinterpret_cast<const float4*>(W + (size_t)j * H_ + 32 * kb + 8 * gq);
    *reinterpret_cast<bf16x8*>(&wlds[u][wm][gq * 8]) = pack8(p[0], p[1]);
  }

  // --- hbuf[0] = tanh(h0)
  for (int e = tid; e < BBLK * H_; e += SC_NW * 64) {
    const int r = e >> 9, k = e & (H_ - 1);
    hbuf[0][r][k] = f2bf(fast_tanh(h0[(size_t)(b0 + r) * H_ + k]));
  }

  // --- inp_cur = inp[t=0] for this lane's 8 output cells (jtp 0..1, r 0..3)
  float inp_cur[2][4];
#pragma unroll
  for (int jtp = 0; jtp < 2; ++jtp) {
    const int col = 128 * w + 16 * (g + 4 * jtp) + m;
#pragma unroll
    for (int r = 0; r < 4; ++r)
      inp_cur[jtp][r] = hid[((size_t)(b0 + r) * T_ + 0) * H_ + col];
  }

  __syncthreads();

  const f32x4 zero = {0.f, 0.f, 0.f, 0.f};
  const int arow = m & 3;

#pragma clang loop unroll(disable)
  for (int t = 0; t < T_; ++t) {
    const int cur = t & 1, nxt = cur ^ 1;

    // prefetch inp for t+1 (skip on last step; loads overlap MFMA phase)
    float inp_nxt[2][4];
    if (t + 1 < T_) {
#pragma unroll
      for (int jtp = 0; jtp < 2; ++jtp) {
        const int col = 128 * w + 16 * (g + 4 * jtp) + m;
#pragma unroll
        for (int r = 0; r < 4; ++r)
          inp_nxt[jtp][r] = hid[((size_t)(b0 + r) * T_ + (t + 1)) * H_ + col];
      }
    }

    f32x4 acc[8];
#pragma unroll
    for (int jt = 0; jt < 8; ++jt) acc[jt] = zero;

    // K loop: kb 0..11 reg; kb12 jt<4 reg, jt>=4 LDS; kb 13..15 LDS
#pragma unroll
    for (int kb = 0; kb < KB_N; ++kb) {
      const bf16x8 a = *reinterpret_cast<const bf16x8*>(&hbuf[cur][arow][32 * kb + 8 * g]);
#pragma unroll
      for (int jt = 0; jt < 8; ++jt) {
        bf16x8 b;
        if (kb < 12)
          b = Wf[kb * 8 + jt];
        else if (kb == 12 && jt < 4)
          b = Wf[96 + jt];
        else {
          const int u = (kb == 12) ? (jt - 4) : (4 + (kb - 13) * 8 + jt);
          b = *reinterpret_cast<const bf16x8*>(&wlds[u][w * 16 + m][g * 8]);
        }
        acc[jt] = __builtin_amdgcn_mfma_f32_16x16x32_bf16(a, b, acc[jt], 0, 0, 0);
      }
    }

    // epilogue: lane (g,m) owns cols 16*(g+4jtp)+m (jtp=0,1), rows r=0..3
#pragma unroll
    for (int jtp = 0; jtp < 2; ++jtp) {
      const int col = 128 * w + 16 * (g + 4 * jtp) + m;
#pragma unroll
      for (int r = 0; r < 4; ++r) {
        float v;
        if (jtp == 0)
          v = (g == 0) ? acc[0][r] : (g == 1) ? acc[1][r] : (g == 2) ? acc[2][r] : acc[3][r];
        else
          v = (g == 0) ? acc[4][r] : (g == 1) ? acc[5][r] : (g == 2) ? acc[6][r] : acc[7][r];
        v += inp_cur[jtp][r];
        hid[((size_t)(b0 + r) * T_ + t) * H_ + col] = v;   // h_next (f32), overwrites inp slot
        hbuf[nxt][r][col] = f2bf(fast_tanh(v));
      }
    }
#pragma unroll
    for (int jtp = 0; jtp < 2; ++jtp)
#pragma unroll
      for (int r = 0; r < 4; ++r) inp_cur[jtp][r] = inp_nxt[jtp][r];

    // drain LDS writes only (vmcnt NOT drained: hid stores / inp loads stay in flight)
    asm volatile("s_waitcnt lgkmcnt(0)" ::: "memory");
    __builtin_amdgcn_s_barrier();
    asm volatile("" ::: "memory");   // fence: keep next-step ds_reads below barrier
  }
}

// ---------------------------------------------------------------------------
// out = hidden @ W_out^T : memory-bound [BT,512]x[512,64] MFMA GEMM.
// ---------------------------------------------------------------------------
#define OP_BLOCKS 1024
#define OP_WAVES  8
__global__ __launch_bounds__(OP_WAVES * 64, 2) void out_proj(
    const float* __restrict__ hid, const float* __restrict__ Wout,
    float* __restrict__ out)
{
  __shared__ __align__(16) short ws[16][NOUT_][32];   // 64 KB

  const int tid  = threadIdx.x;
  const int lane = tid & 63;
  const int w    = tid >> 6;
  const int g    = lane >> 4;
  const int m    = lane & 15;

#pragma unroll
  for (int i = 0; i < 8; ++i) {
    const int c   = tid + OP_WAVES * 64 * i;
    const int kb  = c >> 8;
    const int col = (c >> 2) & 63;
    const int q   = (c & 3) * 8;
    const float4* p = reinterpret_cast<const float4*>(Wout + (size_t)col * H_ + 32 * kb + q);
    *reinterpret_cast<bf16x8*>(&ws[kb][col][q]) = pack8(p[0], p[1]);
  }
  __syncthreads();

  const int wave_id = blockIdx.x * OP_WAVES + w;
  const int NWAVES  = OP_BLOCKS * OP_WAVES;
  const int NTILES  = (B_ * T_) / 16;

  for (int tile = wave_id; tile < NTILES; tile += NWAVES) {
    const size_t row0 = (size_t)tile * 16;
    f32x4 acc[4];
    {
      const float4* p = reinterpret_cast<const float4*>(hid + (row0 + m) * H_ + 8 * g);
      const bf16x8 a = pack8(p[0], p[1]);
      const f32x4 zero = {0.f, 0.f, 0.f, 0.f};
#pragma unroll
      for (int jt = 0; jt < 4; ++jt) {
        const bf16x8 b = *reinterpret_cast<const bf16x8*>(&ws[0][16 * jt + m][8 * g]);
        acc[jt] = __builtin_amdgcn_mfma_f32_16x16x32_bf16(a, b, zero, 0, 0, 0);
      }
    }
#pragma unroll
    for (int kb = 1; kb < 16; ++kb) {
      const float4* p = reinterpret_cast<const float4*>(hid + (row0 + m) * H_ + 32 * kb + 8 * g);
      const bf16x8 a = pack8(p[0], p[1]);
#pragma unroll
      for (int jt = 0; jt < 4; ++jt) {
        const bf16x8 b = *reinterpret_cast<const bf16x8*>(&ws[kb][16 * jt + m][8 * g]);
        acc[jt] = __builtin_amdgcn_mfma_f32_16x16x32_bf16(a, b, acc[jt], 0, 0, 0);
      }
    }
#pragma unroll
    for (int jt = 0; jt < 4; ++jt)
#pragma unroll
      for (int r = 0; r < 4; ++r)
        out[(row0 + 4 * g + r) * NOUT_ + 16 * jt + m] = acc[jt][r];
  }
}

extern "C" void kernel_launch(void* const* d_in, const int* in_sizes, int n_in,
                              void* d_out, int out_size, void* d_ws, size_t ws_size,
                              hipStream_t stream) {
  const float* X    = (const float*)d_in[0];
  const float* h0   = (const float*)d_in[1];
  const float* W    = (const float*)d_in[2];
  const float* Win  = (const float*)d_in[3];
  const float* Wout = (const float*)d_in[4];

  float* out = (float*)d_out;                                   // [B,T,64]
  float* hid = (float*)d_out + (size_t)B_ * T_ * NOUT_;         // [B,T,512] (inp, then h)

  xproj<<<dim3(XP_BLOCKS), dim3(512), 0, stream>>>(X, Win, hid);
  rnn_scan<<<dim3(B_ / BBLK), dim3(SC_NW * 64), 0, stream>>>(h0, W, hid);
  out_proj<<<dim3(OP_BLOCKS), dim3(OP_WAVES * 64), 0, stream>>>(hid, Wout, out);
}

// Round 4
// 2919.455 us; speedup vs baseline: 1.1964x; 1.1964x over previous
//
#include <hip/hip_runtime.h>
#include <stdint.h>

#define B_    256
#define T_    1024
#define H_    512
#define NIN_  64
#define NOUT_ 64

// rnn_scan: 64 blocks x 8 waves; wave owns 64 cols (jt 0..3).
// W residency per wave: kb 0..10 regs (44 units, 176 VGPR),
// kb 11..12 LDS (8 units, 64KB/CU), kb 13..15 streamed from L2 (12 units).
#define SC_NW   8
#define BBLK    4
#define HROW    528     // hbuf row stride in shorts
#define KB_REG  11

typedef __attribute__((ext_vector_type(8))) short bf16x8;
typedef __attribute__((ext_vector_type(4))) float f32x4;

__device__ __forceinline__ short f2bf(float f) {
  uint32_t u = __float_as_uint(f);
  uint32_t r = (u + 0x7FFFu + ((u >> 16) & 1u)) >> 16;
  return (short)(r & 0xFFFFu);
}

__device__ __forceinline__ bf16x8 pack8(float4 lo, float4 hi) {
  bf16x8 s;
  s[0] = f2bf(lo.x); s[1] = f2bf(lo.y); s[2] = f2bf(lo.z); s[3] = f2bf(lo.w);
  s[4] = f2bf(hi.x); s[5] = f2bf(hi.y); s[6] = f2bf(hi.z); s[7] = f2bf(hi.w);
  return s;
}

__device__ __forceinline__ float fast_tanh(float x) {
  float e = __expf(2.0f * x);
  return 1.0f - __fdividef(2.0f, e + 1.0f);
}

// ---------------------------------------------------------------------------
// wprep: pre-convert streamed part of W (kb 13..15) to bf16 fragments.
// Chunk c = (w*12 + su)*64 + lane, su = (kb-13)*4 + jt; 16B per chunk.
// Output lives at the start of the `out` region (overwritten by out_proj).
// ---------------------------------------------------------------------------
__global__ __launch_bounds__(512) void wprep(
    const float* __restrict__ W, short* __restrict__ sw)
{
  const int c = blockIdx.x * 512 + threadIdx.x;   // < 8*12*64 = 6144
  if (c >= 8 * 12 * 64) return;
  const int l  = c & 63;
  const int su = (c >> 6) % 12;
  const int w  = c / (12 * 64);
  const int kb = 13 + (su >> 2);
  const int jt = su & 3;
  const int col = 64 * w + 16 * jt + (l & 15);
  const int k0  = 32 * kb + (l >> 4) * 8;
  const float4* p = reinterpret_cast<const float4*>(W + (size_t)col * H_ + k0);
  *reinterpret_cast<bf16x8*>(sw + (size_t)c * 8) = pack8(p[0], p[1]);
}

// ---------------------------------------------------------------------------
// xproj: inp[b,t,h] = X[b,t,:] @ Win[h,:]  (f32, written into hid region)
// ---------------------------------------------------------------------------
#define XP_BLOCKS 512
__global__ __launch_bounds__(512, 2) void xproj(
    const float* __restrict__ X, const float* __restrict__ Win,
    float* __restrict__ inp)
{
  const int tid  = threadIdx.x;
  const int lane = tid & 63;
  const int w    = tid >> 6;
  const int g    = lane >> 4;
  const int m    = lane & 15;

  bf16x8 Bf[2][4];
#pragma unroll
  for (int kb = 0; kb < 2; ++kb)
#pragma unroll
    for (int jt = 0; jt < 4; ++jt) {
      const int j = 64 * w + 16 * jt + m;
      const float4* p = reinterpret_cast<const float4*>(Win + (size_t)j * NIN_ + 32 * kb + 8 * g);
      Bf[kb][jt] = pack8(p[0], p[1]);
    }

  const int NTILES = (B_ * T_) / 16;
  const f32x4 zero = {0.f, 0.f, 0.f, 0.f};

  for (int tile = blockIdx.x; tile < NTILES; tile += XP_BLOCKS) {
    const size_t row0 = (size_t)tile * 16;
    f32x4 acc[4];
    {
      const float4* p = reinterpret_cast<const float4*>(X + (row0 + m) * NIN_ + 8 * g);
      const bf16x8 a = pack8(p[0], p[1]);
#pragma unroll
      for (int jt = 0; jt < 4; ++jt)
        acc[jt] = __builtin_amdgcn_mfma_f32_16x16x32_bf16(a, Bf[0][jt], zero, 0, 0, 0);
    }
    {
      const float4* p = reinterpret_cast<const float4*>(X + (row0 + m) * NIN_ + 32 + 8 * g);
      const bf16x8 a = pack8(p[0], p[1]);
#pragma unroll
      for (int jt = 0; jt < 4; ++jt)
        acc[jt] = __builtin_amdgcn_mfma_f32_16x16x32_bf16(a, Bf[1][jt], acc[jt], 0, 0, 0);
    }
#pragma unroll
    for (int jt = 0; jt < 4; ++jt)
#pragma unroll
      for (int r = 0; r < 4; ++r)
        inp[(row0 + 4 * g + r) * H_ + 64 * w + 16 * jt + m] = acc[jt][r];
  }
}

// ---------------------------------------------------------------------------
// rnn_scan
// ---------------------------------------------------------------------------
__global__ __launch_bounds__(SC_NW * 64, 2) void rnn_scan(
    const float* __restrict__ h0, const float* __restrict__ W,
    float* __restrict__ hid, const short* __restrict__ swbuf)
{
  __shared__ __align__(16) short wlds[SC_NW * 8 * 64 * 8];   // 64 KB: kb 11,12
  __shared__ __align__(16) short hbuf[2][BBLK][HROW];        // 8.25 KB

  const int tid  = threadIdx.x;
  const int lane = tid & 63;
  const int w    = tid >> 6;    // wave 0..7
  const int g    = lane >> 4;
  const int m    = lane & 15;
  const int b0   = blockIdx.x * BBLK;

  // --- register-resident W: kb 0..10, jt 0..3 (B[k][col] = W[col][k])
  bf16x8 Wf[KB_REG * 4];
#pragma unroll
  for (int kb = 0; kb < KB_REG; ++kb)
#pragma unroll
    for (int jt = 0; jt < 4; ++jt) {
      const int j = 64 * w + 16 * jt + m;
      const float4* p = reinterpret_cast<const float4*>(W + (size_t)j * H_ + 32 * kb + 8 * g);
      Wf[kb * 4 + jt] = pack8(p[0], p[1]);
    }

  // --- LDS-resident W: kb 11,12 as per-lane-linear fragments
  // unit (ww, u) at wlds[((ww*8+u)*64+l)*8], u = (kb-11)*4+jt
#pragma unroll
  for (int i = 0; i < 8; ++i) {
    const int c  = tid + 512 * i;          // < 4096
    const int l  = c & 63;
    const int u  = (c >> 6) & 7;
    const int ww = c >> 9;
    const int kb = KB_REG + (u >> 2);
    const int jt = u & 3;
    const int col = 64 * ww + 16 * jt + (l & 15);
    const int k0  = 32 * kb + (l >> 4) * 8;
    const float4* p = reinterpret_cast<const float4*>(W + (size_t)col * H_ + k0);
    *reinterpret_cast<bf16x8*>(&wlds[((size_t)(ww * 8 + u) * 64 + l) * 8]) = pack8(p[0], p[1]);
  }

  // --- hbuf[0] = tanh(h0)
  for (int e = tid; e < BBLK * H_; e += SC_NW * 64) {
    const int r = e >> 9, k = e & (H_ - 1);
    hbuf[0][r][k] = f2bf(fast_tanh(h0[(size_t)(b0 + r) * H_ + k]));
  }

  // --- stream buffers: X holds kb13 (su 0..3), Y holds kb14 (su 4..7)
  const bf16x8* SW = reinterpret_cast<const bf16x8*>(swbuf);
  const int sbase = w * 12 * 64 + lane;
  bf16x8 Xb0 = SW[sbase + 0 * 64], Xb1 = SW[sbase + 1 * 64],
         Xb2 = SW[sbase + 2 * 64], Xb3 = SW[sbase + 3 * 64];
  bf16x8 Yb0 = SW[sbase + 4 * 64], Yb1 = SW[sbase + 5 * 64],
         Yb2 = SW[sbase + 6 * 64], Yb3 = SW[sbase + 7 * 64];

  // --- inp_cur for t=0: lane owns col = 64w+lane, rows 0..3
  float inp_cur[4];
#pragma unroll
  for (int r = 0; r < 4; ++r)
    inp_cur[r] = hid[((size_t)(b0 + r) * T_ + 0) * H_ + 64 * w + lane];

  __syncthreads();

  const f32x4 zero = {0.f, 0.f, 0.f, 0.f};
  const int arow = m & 3;

#pragma clang loop unroll(disable)
  for (int t = 0; t < T_; ++t) {
    const int cur = t & 1, nxt = cur ^ 1;
    const short* hr = &hbuf[cur][arow][0];

    f32x4 acc[4];

    // Phase 0: consume X = kb13 (prefetched last step); reissue X <- kb15
    {
      const bf16x8 a = *reinterpret_cast<const bf16x8*>(hr + 32 * 13 + 8 * g);
      acc[0] = __builtin_amdgcn_mfma_f32_16x16x32_bf16(a, Xb0, zero, 0, 0, 0);
      acc[1] = __builtin_amdgcn_mfma_f32_16x16x32_bf16(a, Xb1, zero, 0, 0, 0);
      acc[2] = __builtin_amdgcn_mfma_f32_16x16x32_bf16(a, Xb2, zero, 0, 0, 0);
      acc[3] = __builtin_amdgcn_mfma_f32_16x16x32_bf16(a, Xb3, zero, 0, 0, 0);
    }
    Xb0 = SW[sbase + 8 * 64];  Xb1 = SW[sbase + 9 * 64];
    Xb2 = SW[sbase + 10 * 64]; Xb3 = SW[sbase + 11 * 64];

    // inp prefetch for t+1
    float inp_nxt[4];
    if (t + 1 < T_) {
#pragma unroll
      for (int r = 0; r < 4; ++r)
        inp_nxt[r] = hid[((size_t)(b0 + r) * T_ + (t + 1)) * H_ + 64 * w + lane];
    }

    // Phase 1: register kbs 0..10
#pragma unroll
    for (int kb = 0; kb < KB_REG; ++kb) {
      const bf16x8 a = *reinterpret_cast<const bf16x8*>(hr + 32 * kb + 8 * g);
      acc[0] = __builtin_amdgcn_mfma_f32_16x16x32_bf16(a, Wf[kb * 4 + 0], acc[0], 0, 0, 0);
      acc[1] = __builtin_amdgcn_mfma_f32_16x16x32_bf16(a, Wf[kb * 4 + 1], acc[1], 0, 0, 0);
      acc[2] = __builtin_amdgcn_mfma_f32_16x16x32_bf16(a, Wf[kb * 4 + 2], acc[2], 0, 0, 0);
      acc[3] = __builtin_amdgcn_mfma_f32_16x16x32_bf16(a, Wf[kb * 4 + 3], acc[3], 0, 0, 0);
    }

    // Phase 1b: LDS kbs 11,12
#pragma unroll
    for (int kk = 0; kk < 2; ++kk) {
      const int kb = KB_REG + kk;
      const bf16x8 a = *reinterpret_cast<const bf16x8*>(hr + 32 * kb + 8 * g);
#pragma unroll
      for (int jt = 0; jt < 4; ++jt) {
        const bf16x8 b = *reinterpret_cast<const bf16x8*>(
            &wlds[((size_t)(w * 8 + kk * 4 + jt) * 64 + lane) * 8]);
        acc[jt] = __builtin_amdgcn_mfma_f32_16x16x32_bf16(a, b, acc[jt], 0, 0, 0);
      }
    }

    // Phase 2: consume Y = kb14; reissue Y <- kb14 (for next step)
    {
      const bf16x8 a = *reinterpret_cast<const bf16x8*>(hr + 32 * 14 + 8 * g);
      acc[0] = __builtin_amdgcn_mfma_f32_16x16x32_bf16(a, Yb0, acc[0], 0, 0, 0);
      acc[1] = __builtin_amdgcn_mfma_f32_16x16x32_bf16(a, Yb1, acc[1], 0, 0, 0);
      acc[2] = __builtin_amdgcn_mfma_f32_16x16x32_bf16(a, Yb2, acc[2], 0, 0, 0);
      acc[3] = __builtin_amdgcn_mfma_f32_16x16x32_bf16(a, Yb3, acc[3], 0, 0, 0);
    }
    Yb0 = SW[sbase + 4 * 64]; Yb1 = SW[sbase + 5 * 64];
    Yb2 = SW[sbase + 6 * 64]; Yb3 = SW[sbase + 7 * 64];

    // Phase 3: consume X = kb15; reissue X <- kb13 (for next step)
    {
      const bf16x8 a = *reinterpret_cast<const bf16x8*>(hr + 32 * 15 + 8 * g);
      acc[0] = __builtin_amdgcn_mfma_f32_16x16x32_bf16(a, Xb0, acc[0], 0, 0, 0);
      acc[1] = __builtin_amdgcn_mfma_f32_16x16x32_bf16(a, Xb1, acc[1], 0, 0, 0);
      acc[2] = __builtin_amdgcn_mfma_f32_16x16x32_bf16(a, Xb2, acc[2], 0, 0, 0);
      acc[3] = __builtin_amdgcn_mfma_f32_16x16x32_bf16(a, Xb3, acc[3], 0, 0, 0);
    }
    Xb0 = SW[sbase + 0 * 64]; Xb1 = SW[sbase + 1 * 64];
    Xb2 = SW[sbase + 2 * 64]; Xb3 = SW[sbase + 3 * 64];

    // Epilogue: lane owns col = 64w+lane (jt == g); D row 4g+r = batch row r
#pragma unroll
    for (int r = 0; r < 4; ++r) {
      float v = acc[0][r];
      v = (g == 1) ? acc[1][r] : v;
      v = (g == 2) ? acc[2][r] : v;
      v = (g == 3) ? acc[3][r] : v;
      v += inp_cur[r];
      hid[((size_t)(b0 + r) * T_ + t) * H_ + 64 * w + lane] = v;
      hbuf[nxt][r][64 * w + lane] = f2bf(fast_tanh(v));
    }
#pragma unroll
    for (int r = 0; r < 4; ++r) inp_cur[r] = inp_nxt[r];

    // drain LDS ops only; vmcnt stays in flight (hid stores, stream loads)
    asm volatile("s_waitcnt lgkmcnt(0)" ::: "memory");
    __builtin_amdgcn_s_barrier();
    asm volatile("" ::: "memory");
  }
}

// ---------------------------------------------------------------------------
// out = hidden @ W_out^T : memory-bound [BT,512]x[512,64] MFMA GEMM.
// ---------------------------------------------------------------------------
#define OP_BLOCKS 1024
#define OP_WAVES  8
__global__ __launch_bounds__(OP_WAVES * 64, 2) void out_proj(
    const float* __restrict__ hid, const float* __restrict__ Wout,
    float* __restrict__ out)
{
  __shared__ __align__(16) short ws[16][NOUT_][32];   // 64 KB

  const int tid  = threadIdx.x;
  const int lane = tid & 63;
  const int w    = tid >> 6;
  const int g    = lane >> 4;
  const int m    = lane & 15;

#pragma unroll
  for (int i = 0; i < 8; ++i) {
    const int c   = tid + OP_WAVES * 64 * i;
    const int kb  = c >> 8;
    const int col = (c >> 2) & 63;
    const int q   = (c & 3) * 8;
    const float4* p = reinterpret_cast<const float4*>(Wout + (size_t)col * H_ + 32 * kb + q);
    *reinterpret_cast<bf16x8*>(&ws[kb][col][q]) = pack8(p[0], p[1]);
  }
  __syncthreads();

  const int wave_id = blockIdx.x * OP_WAVES + w;
  const int NWAVES  = OP_BLOCKS * OP_WAVES;
  const int NTILES  = (B_ * T_) / 16;

  for (int tile = wave_id; tile < NTILES; tile += NWAVES) {
    const size_t row0 = (size_t)tile * 16;
    f32x4 acc[4];
    {
      const float4* p = reinterpret_cast<const float4*>(hid + (row0 + m) * H_ + 8 * g);
      const bf16x8 a = pack8(p[0], p[1]);
      const f32x4 zero = {0.f, 0.f, 0.f, 0.f};
#pragma unroll
      for (int jt = 0; jt < 4; ++jt) {
        const bf16x8 b = *reinterpret_cast<const bf16x8*>(&ws[0][16 * jt + m][8 * g]);
        acc[jt] = __builtin_amdgcn_mfma_f32_16x16x32_bf16(a, b, zero, 0, 0, 0);
      }
    }
#pragma unroll
    for (int kb = 1; kb < 16; ++kb) {
      const float4* p = reinterpret_cast<const float4*>(hid + (row0 + m) * H_ + 32 * kb + 8 * g);
      const bf16x8 a = pack8(p[0], p[1]);
#pragma unroll
      for (int jt = 0; jt < 4; ++jt) {
        const bf16x8 b = *reinterpret_cast<const bf16x8*>(&ws[kb][16 * jt + m][8 * g]);
        acc[jt] = __builtin_amdgcn_mfma_f32_16x16x32_bf16(a, b, acc[jt], 0, 0, 0);
      }
    }
#pragma unroll
    for (int jt = 0; jt < 4; ++jt)
#pragma unroll
      for (int r = 0; r < 4; ++r)
        out[(row0 + 4 * g + r) * NOUT_ + 16 * jt + m] = acc[jt][r];
  }
}

extern "C" void kernel_launch(void* const* d_in, const int* in_sizes, int n_in,
                              void* d_out, int out_size, void* d_ws, size_t ws_size,
                              hipStream_t stream) {
  const float* X    = (const float*)d_in[0];
  const float* h0   = (const float*)d_in[1];
  const float* W    = (const float*)d_in[2];
  const float* Win  = (const float*)d_in[3];
  const float* Wout = (const float*)d_in[4];

  float* out = (float*)d_out;                                   // [B,T,64]
  float* hid = (float*)d_out + (size_t)B_ * T_ * NOUT_;         // [B,T,512]
  short* sw  = (short*)d_out;                                    // 96 KB W-stream scratch
                                                                 // (inside `out`, overwritten by out_proj)

  wprep<<<dim3(12), dim3(512), 0, stream>>>(W, sw);
  xproj<<<dim3(XP_BLOCKS), dim3(512), 0, stream>>>(X, Win, hid);
  rnn_scan<<<dim3(B_ / BBLK), dim3(SC_NW * 64), 0, stream>>>(h0, W, hid, sw);
  out_proj<<<dim3(OP_BLOCKS), dim3(OP_WAVES * 64), 0, stream>>>(hid, Wout, out);
}